// Round 8
// baseline (1091.197 us; speedup 1.0000x reference)
//
#include <hip/hip_runtime.h>
#include <hip/hip_bf16.h>
#include <cstdint>

typedef __attribute__((ext_vector_type(8))) short short8;
typedef __attribute__((ext_vector_type(4))) float f32x4;

#define KD     1024     // GEMM K
#define D_DIM  1024
#define M_TOT  16384    // B*L
#define L_DIM  4096
#define NG     9        // gate groups
#define NF     18       // 9 groups * 2 sixteen-wide frags (32 d-cols per block)
#define BROWS  288      // NF*16 B-rows staged per K-step
#define ASLOTS 8        // 128 rows / 16 rows-per-1KB-slot
#define TSLOTS 26       // 8 A + 18 B

__constant__ int c_offs[9] = {0, -32, -16, -4, -1, 1, 4, 16, 32};

// async global->LDS, 16B per lane. LDS dest wave-uniform base; HW adds lane*16.
__device__ __forceinline__ void gload_lds16(const unsigned short* g, unsigned short* l) {
    __builtin_amdgcn_global_load_lds((const __attribute__((address_space(1))) unsigned int*)(g),
                                     (__attribute__((address_space(3))) unsigned int*)(l),
                                     16, 0, 0);
}

// ---------- f32 -> bf16 convert ----------
__global__ __launch_bounds__(256) void cvt_kernel(const float* __restrict__ src,
                                                  unsigned short* __restrict__ dst,
                                                  long total)
{
    long i4 = ((long)blockIdx.x * 256 + threadIdx.x) * 4;
    if (i4 >= total) return;
    float4 f = *(const float4*)&src[i4];
    __hip_bfloat16 h0 = __float2bfloat16(f.x), h1 = __float2bfloat16(f.y),
                   h2 = __float2bfloat16(f.z), h3 = __float2bfloat16(f.w);
    ushort4 h;
    h.x = *(unsigned short*)&h0; h.y = *(unsigned short*)&h1;
    h.z = *(unsigned short*)&h2; h.w = *(unsigned short*)&h3;
    *(ushort4*)&dst[i4] = h;
}

// ---------- single-buffer 128x128 tile core (kept for v_gemm; validated r3) ----------
__device__ __forceinline__ void gemm_tile(const unsigned short* __restrict__ A,
                                          const unsigned short* __restrict__ Bm,
                                          int m0,
                                          unsigned short* As, unsigned short* Bs,
                                          f32x4 acc[4][4])
{
    const int tid  = threadIdx.x;
    const int lane = tid & 63;
    const int wid  = tid >> 6;
    const int wr = wid >> 1, wc = wid & 1;
    const int lg = lane >> 4, lr = lane & 15;

    const int t0   = wid * 2;
    const int row0 = t0 * 16 + (lane >> 2);
    const int row1 = row0 + 16;
    const int sch  = lane & 3;
    const int kc0  = sch ^ ((row0 >> 1) & 3);
    const int kc1  = sch ^ ((row1 >> 1) & 3);

    const unsigned short* gA0 = A  + (size_t)(m0 + row0) * KD + kc0 * 8;
    const unsigned short* gA1 = A  + (size_t)(m0 + row1) * KD + kc1 * 8;
    const unsigned short* gB0 = Bm + (size_t)row0 * KD + kc0 * 8;
    const unsigned short* gB1 = Bm + (size_t)row1 * KD + kc1 * 8;

    unsigned short* lA0 = As + t0 * 512;
    unsigned short* lA1 = As + (t0 + 1) * 512;
    unsigned short* lB0 = Bs + t0 * 512;
    unsigned short* lB1 = Bs + (t0 + 1) * 512;

    const int raBase = wr * 64 + lr;
    const int rbBase = wc * 64 + lr;

    for (int kt = 0; kt < KD / 32; ++kt) {
        const int k0 = kt * 32;
        gload_lds16(gA0 + k0, lA0);
        gload_lds16(gA1 + k0, lA1);
        gload_lds16(gB0 + k0, lB0);
        gload_lds16(gB1 + k0, lB1);
        __syncthreads();

        short8 af[4], bfr[4];
#pragma unroll
        for (int i = 0; i < 4; ++i) {
            int ra = raBase + i * 16;
            af[i] = *(const short8*)&As[ra * 32 + (lg ^ ((ra >> 1) & 3)) * 8];
        }
#pragma unroll
        for (int j = 0; j < 4; ++j) {
            int rb = rbBase + j * 16;
            bfr[j] = *(const short8*)&Bs[rb * 32 + (lg ^ ((rb >> 1) & 3)) * 8];
        }
#pragma unroll
        for (int i = 0; i < 4; ++i)
#pragma unroll
            for (int j = 0; j < 4; ++j)
                acc[i][j] = __builtin_amdgcn_mfma_f32_16x16x32_bf16(af[i], bfr[j], acc[i][j], 0, 0, 0);
        __syncthreads();
    }
}

// ---------- v = x @ value_W^T ----------
__global__ __launch_bounds__(256) void v_gemm(const unsigned short* __restrict__ A,
                                              const unsigned short* __restrict__ Bv,
                                              float* __restrict__ v_out)
{
    __shared__ __align__(16) unsigned short As[128 * 32];
    __shared__ __align__(16) unsigned short Bs[128 * 32];
    const int m0 = blockIdx.y * 128;
    const int e0 = blockIdx.x * 128;
    f32x4 acc[4][4];
#pragma unroll
    for (int i = 0; i < 4; ++i)
#pragma unroll
        for (int j = 0; j < 4; ++j)
            acc[i][j] = {0.f, 0.f, 0.f, 0.f};

    gemm_tile(A, Bv + (size_t)e0 * KD, m0, As, Bs, acc);

    const int lane = threadIdx.x & 63, wid = threadIdx.x >> 6;
    const int wr = wid >> 1, wc = wid & 1, lg = lane >> 4, lr = lane & 15;
#pragma unroll
    for (int i = 0; i < 4; ++i)
#pragma unroll
        for (int j = 0; j < 4; ++j)
#pragma unroll
            for (int r = 0; r < 4; ++r) {
                int row = m0 + wr * 64 + i * 16 + lg * 4 + r;
                int col = e0 + wc * 64 + j * 16 + lr;
                v_out[(size_t)row * D_DIM + col] = acc[i][j][r];
            }
}

// ---------- gates: one K-pass over all 9 groups, 2-phase dbuf, fused mix epilogue ----------
// Block tile: 128 rows x 32 d-cols x 9 groups (logits 128x288).
// 4 waves, wave w owns rows [w*32, w*32+32) (M_rep=2), all 18 B-frags.
__global__ __launch_bounds__(256, 2) void gates_gemm(const unsigned short* __restrict__ A,
                                                     const unsigned short* __restrict__ Bg,
                                                     const float* __restrict__ v_ws,
                                                     float* __restrict__ out)
{
    __shared__ __align__(16) unsigned short As[2][128 * 32];   // 16 KB
    __shared__ __align__(16) unsigned short Bs[2][BROWS * 32]; // 36 KB
    const int m0 = blockIdx.y * 128;
    const int d0 = blockIdx.x * 32;
    const int tid = threadIdx.x;
    const int lane = tid & 63, w = tid >> 6;
    const int lg = lane >> 4, lr = lane & 15;

    // --- per-wave staging descriptors: slots s = w, w+4, ... < 26 (6 or 7 each)
    const unsigned short* gsrc[7];
    unsigned short* lbase[7];
    int lstride[7];
    int ns = 0;
    {
        const int rowoff = lane >> 2;   // 0..15 within slot
        const int sch = lane & 3;       // 16B chunk within 64B row
#pragma unroll
        for (int i = 0; i < 7; ++i) {
            int s = w + i * 4;
            if (s < TSLOTS) {
                if (s < ASLOTS) {
                    int row = s * 16 + rowoff;                 // 0..127
                    int kc = sch ^ ((row >> 1) & 3);           // pre-swizzled chunk
                    gsrc[ns] = A + (size_t)(m0 + row) * KD + kc * 8;
                    lbase[ns] = &As[0][s * 512];
                    lstride[ns] = 128 * 32;
                } else {
                    int t = s - ASLOTS;
                    int rb = t * 16 + rowoff;                  // 0..287
                    int g = rb >> 5, dc = rb & 31;
                    int kc = sch ^ ((rb >> 1) & 3);
                    gsrc[ns] = Bg + (size_t)(g * D_DIM + d0 + dc) * KD + kc * 8;
                    lbase[ns] = &Bs[0][t * 512];
                    lstride[ns] = BROWS * 32;
                }
                ++ns;
            }
        }
    }

    auto stage = [&](int kt, int buf) {
#pragma unroll
        for (int i = 0; i < 7; ++i)
            if (i < ns)
                gload_lds16(gsrc[i] + kt * 32, lbase[i] + buf * lstride[i]);
    };

    f32x4 acc[2][NF];
#pragma unroll
    for (int mf = 0; mf < 2; ++mf)
#pragma unroll
        for (int nf = 0; nf < NF; ++nf)
            acc[mf][nf] = {0.f, 0.f, 0.f, 0.f};

    const int raBase = w * 32 + lr;

    stage(0, 0);
    __syncthreads();

    int buf = 0;
    for (int kt = 0; kt < KD / 32; ++kt) {
        if (kt < KD / 32 - 1) stage(kt + 1, buf ^ 1);   // prefetch next tile into other buffer

        const unsigned short* Ab = &As[0][0] + buf * (128 * 32);
        const unsigned short* Bb = &Bs[0][0] + buf * (BROWS * 32);

        short8 af0, af1;
        {
            int ra = raBase;
            af0 = *(const short8*)&Ab[ra * 32 + (lg ^ ((ra >> 1) & 3)) * 8];
            ra = raBase + 16;
            af1 = *(const short8*)&Ab[ra * 32 + (lg ^ ((ra >> 1) & 3)) * 8];
        }
#pragma unroll
        for (int nf = 0; nf < NF; ++nf) {
            int rb = nf * 16 + lr;
            short8 bf = *(const short8*)&Bb[rb * 32 + (lg ^ ((rb >> 1) & 3)) * 8];
            acc[0][nf] = __builtin_amdgcn_mfma_f32_16x16x32_bf16(af0, bf, acc[0][nf], 0, 0, 0);
            acc[1][nf] = __builtin_amdgcn_mfma_f32_16x16x32_bf16(af1, bf, acc[1][nf], 0, 0, 0);
        }
        __syncthreads();   // drains vmcnt (next-tile staging) + lgkmcnt (our reads)
        buf ^= 1;
    }

    // --- epilogue: sigmoid + shifted-v gather + sum over 9 groups, write once
#pragma unroll
    for (int mf = 0; mf < 2; ++mf)
#pragma unroll
        for (int h = 0; h < 2; ++h) {
            const int col = d0 + h * 16 + lr;
#pragma unroll
            for (int r = 0; r < 4; ++r) {
                const int row = m0 + w * 32 + mf * 16 + (lane >> 4) * 4 + r;
                float o = 0.f;
#pragma unroll
                for (int g = 0; g < NG; ++g) {
                    int srow = (row & ~(L_DIM - 1)) | ((row + c_offs[g] + L_DIM) & (L_DIM - 1));
                    float gate = 1.f / (1.f + __expf(-acc[mf][g * 2 + h][r]));
                    o += gate * v_ws[(size_t)srow * D_DIM + col];
                }
                out[(size_t)row * D_DIM + col] = o;
            }
        }
}

// ---------- in-place LayerNorm over last dim ----------
__global__ __launch_bounds__(256) void ln_kernel(float* __restrict__ out,
                                                 const float* __restrict__ gamma,
                                                 const float* __restrict__ beta)
{
    const int row = blockIdx.x;
    const int tid = threadIdx.x;
    float4 v = *(float4*)&out[(size_t)row * D_DIM + tid * 4];
    float s  = v.x + v.y + v.z + v.w;
    float s2 = v.x * v.x + v.y * v.y + v.z * v.z + v.w * v.w;
#pragma unroll
    for (int off = 32; off > 0; off >>= 1) {
        s  += __shfl_down(s, off, 64);
        s2 += __shfl_down(s2, off, 64);
    }
    __shared__ float sh[8];
    const int wid = tid >> 6, lane = tid & 63;
    if (lane == 0) { sh[wid] = s; sh[4 + wid] = s2; }
    __syncthreads();
    if (tid == 0) {
        float ts = sh[0] + sh[1] + sh[2] + sh[3];
        float t2 = sh[4] + sh[5] + sh[6] + sh[7];
        sh[0] = ts; sh[1] = t2;
    }
    __syncthreads();
    const float mean = sh[0] * (1.f / (float)D_DIM);
    const float var  = sh[1] * (1.f / (float)D_DIM) - mean * mean;
    const float inv  = rsqrtf(var + 1e-5f);
    float4 g = *(const float4*)&gamma[tid * 4];
    float4 b = *(const float4*)&beta[tid * 4];
    v.x = (v.x - mean) * inv * g.x + b.x;
    v.y = (v.y - mean) * inv * g.y + b.y;
    v.z = (v.z - mean) * inv * g.z + b.z;
    v.w = (v.w - mean) * inv * g.w + b.w;
    *(float4*)&out[(size_t)row * D_DIM + tid * 4] = v;
}

extern "C" void kernel_launch(void* const* d_in, const int* in_sizes, int n_in,
                              void* d_out, int out_size, void* d_ws, size_t ws_size,
                              hipStream_t stream) {
    const float* x       = (const float*)d_in[0];   // (4,4096,1024)
    const float* gate_W  = (const float*)d_in[1];   // (9216,1024)
    const float* value_W = (const float*)d_in[2];   // (1024,1024)
    const float* gamma   = (const float*)d_in[3];   // (1024,)
    const float* beta    = (const float*)d_in[4];   // (1024,)
    float* out = (float*)d_out;                     // (4,4096,1024) f32

    char* ws = (char*)d_ws;
    unsigned short* a_bf = (unsigned short*)ws;                      // 32 MB
    unsigned short* bw_v = (unsigned short*)(ws + 33554432);         //  2 MB
    unsigned short* bw_g = (unsigned short*)(ws + 35651584);         // 18 MB
    float*          v_ws = (float*)(ws + 54525952);                  // 64 MB

    // 1. convert inputs to bf16
    cvt_kernel<<<16384, 256, 0, stream>>>(x,       a_bf, (long)M_TOT * 1024);
    cvt_kernel<<<1024,  256, 0, stream>>>(value_W, bw_v, (long)1024  * 1024);
    cvt_kernel<<<9216,  256, 0, stream>>>(gate_W,  bw_g, (long)9216  * 1024);

    // 2. v = x @ value_W^T   (M=16384, N=1024, K=1024)
    v_gemm<<<dim3(8, 128), 256, 0, stream>>>(a_bf, bw_v, v_ws);

    // 3. gates GEMM (all 9 groups in one K-pass) + sigmoid + shift-gather -> pre-LN out
    gates_gemm<<<dim3(D_DIM / 32, M_TOT / 128), 256, 0, stream>>>(a_bf, bw_g, v_ws, out);

    // 4. LayerNorm in place
    ln_kernel<<<16384, 256, 0, stream>>>(out, gamma, beta);
}

// Round 11
// 588.618 us; speedup vs baseline: 1.8538x; 1.8538x over previous
//
#include <hip/hip_runtime.h>
#include <hip/hip_bf16.h>
#include <cstdint>

typedef __attribute__((ext_vector_type(8))) short short8;
typedef __attribute__((ext_vector_type(4))) float f32x4;

#define KD     1024     // GEMM K
#define D_DIM  1024
#define M_TOT  16384    // B*L
#define L_DIM  4096
#define NG     9        // gate groups

// ---- gates kernel geometry: 256 rows x 32 dcols x 9 groups, BK=64, 8 waves ----
#define GBM    256
#define GDC    32
#define GBN    288      // NG*GDC B-rows per K-step
#define GBK    64
#define GASLOT 32       // A slots (1KB each: 8 rows x 128B)
#define GTSLOT 68       // 32 A + 36 B
#define GBUF_USHORT 34816   // 68KB per buffer in ushorts
#define GB_OFF_USHORT 16384 // B region starts at 32KB

__constant__ int c_offs[9] = {0, -32, -16, -4, -1, 1, 4, 16, 32};

// async global->LDS, 16B per lane. LDS dest wave-uniform base; HW adds lane*16.
__device__ __forceinline__ void gload_lds16(const unsigned short* g, unsigned short* l) {
    __builtin_amdgcn_global_load_lds((const __attribute__((address_space(1))) unsigned int*)(g),
                                     (__attribute__((address_space(3))) unsigned int*)(l),
                                     16, 0, 0);
}

// ---------- f32 -> bf16 convert ----------
__global__ __launch_bounds__(256) void cvt_kernel(const float* __restrict__ src,
                                                  unsigned short* __restrict__ dst,
                                                  long total)
{
    long i4 = ((long)blockIdx.x * 256 + threadIdx.x) * 4;
    if (i4 >= total) return;
    float4 f = *(const float4*)&src[i4];
    __hip_bfloat16 h0 = __float2bfloat16(f.x), h1 = __float2bfloat16(f.y),
                   h2 = __float2bfloat16(f.z), h3 = __float2bfloat16(f.w);
    ushort4 h;
    h.x = *(unsigned short*)&h0; h.y = *(unsigned short*)&h1;
    h.z = *(unsigned short*)&h2; h.w = *(unsigned short*)&h3;
    *(ushort4*)&dst[i4] = h;
}

// ---------- single-buffer 128x128 tile core (validated r3; used by v_gemm) ----------
__device__ __forceinline__ void gemm_tile(const unsigned short* __restrict__ A,
                                          const unsigned short* __restrict__ Bm,
                                          int m0,
                                          unsigned short* As, unsigned short* Bs,
                                          f32x4 acc[4][4])
{
    const int tid  = threadIdx.x;
    const int lane = tid & 63;
    const int wid  = tid >> 6;
    const int wr = wid >> 1, wc = wid & 1;
    const int lg = lane >> 4, lr = lane & 15;

    const int t0   = wid * 2;
    const int row0 = t0 * 16 + (lane >> 2);
    const int row1 = row0 + 16;
    const int sch  = lane & 3;
    const int kc0  = sch ^ ((row0 >> 1) & 3);
    const int kc1  = sch ^ ((row1 >> 1) & 3);

    const unsigned short* gA0 = A  + (size_t)(m0 + row0) * KD + kc0 * 8;
    const unsigned short* gA1 = A  + (size_t)(m0 + row1) * KD + kc1 * 8;
    const unsigned short* gB0 = Bm + (size_t)row0 * KD + kc0 * 8;
    const unsigned short* gB1 = Bm + (size_t)row1 * KD + kc1 * 8;

    unsigned short* lA0 = As + t0 * 512;
    unsigned short* lA1 = As + (t0 + 1) * 512;
    unsigned short* lB0 = Bs + t0 * 512;
    unsigned short* lB1 = Bs + (t0 + 1) * 512;

    const int raBase = wr * 64 + lr;
    const int rbBase = wc * 64 + lr;

    for (int kt = 0; kt < KD / 32; ++kt) {
        const int k0 = kt * 32;
        gload_lds16(gA0 + k0, lA0);
        gload_lds16(gA1 + k0, lA1);
        gload_lds16(gB0 + k0, lB0);
        gload_lds16(gB1 + k0, lB1);
        __syncthreads();

        short8 af[4], bfr[4];
#pragma unroll
        for (int i = 0; i < 4; ++i) {
            int ra = raBase + i * 16;
            af[i] = *(const short8*)&As[ra * 32 + (lg ^ ((ra >> 1) & 3)) * 8];
        }
#pragma unroll
        for (int j = 0; j < 4; ++j) {
            int rb = rbBase + j * 16;
            bfr[j] = *(const short8*)&Bs[rb * 32 + (lg ^ ((rb >> 1) & 3)) * 8];
        }
#pragma unroll
        for (int i = 0; i < 4; ++i)
#pragma unroll
            for (int j = 0; j < 4; ++j)
                acc[i][j] = __builtin_amdgcn_mfma_f32_16x16x32_bf16(af[i], bfr[j], acc[i][j], 0, 0, 0);
        __syncthreads();
    }
}

// ---------- v = x @ value_W^T ----------
__global__ __launch_bounds__(256) void v_gemm(const unsigned short* __restrict__ A,
                                              const unsigned short* __restrict__ Bv,
                                              float* __restrict__ v_out)
{
    __shared__ __align__(16) unsigned short As[128 * 32];
    __shared__ __align__(16) unsigned short Bs[128 * 32];
    const int m0 = blockIdx.y * 128;
    const int e0 = blockIdx.x * 128;
    f32x4 acc[4][4];
#pragma unroll
    for (int i = 0; i < 4; ++i)
#pragma unroll
        for (int j = 0; j < 4; ++j)
            acc[i][j] = {0.f, 0.f, 0.f, 0.f};

    gemm_tile(A, Bv + (size_t)e0 * KD, m0, As, Bs, acc);

    const int lane = threadIdx.x & 63, wid = threadIdx.x >> 6;
    const int wr = wid >> 1, wc = wid & 1, lg = lane >> 4, lr = lane & 15;
#pragma unroll
    for (int i = 0; i < 4; ++i)
#pragma unroll
        for (int j = 0; j < 4; ++j)
#pragma unroll
            for (int r = 0; r < 4; ++r) {
                int row = m0 + wr * 64 + i * 16 + lg * 4 + r;
                int col = e0 + wc * 64 + j * 16 + lr;
                v_out[(size_t)row * D_DIM + col] = acc[i][j][r];
            }
}

// ---------- gates: 256x32x9 tile, BK=64, 8 waves, 2-phase dbuf, fused mix epilogue ----------
// Wave grid 4M x 2N: wave w (wr=w>>1, wn=w&1) owns rows [wr*64, wr*64+64) x
// (9 groups x 16 cols at d0+wn*16). acc[4 Mfrag][9 group] = 144 VGPR.
// Per K-step/wave: 26 ds_read_b128, 72 MFMA -> drain hides under compute.
// LDS swizzle (G4 recipe for 128B rows): chunk16 ^= (row&7), both sides (rule 21).
__global__ __launch_bounds__(512, 2) void gates_gemm(const unsigned short* __restrict__ A,
                                                     const unsigned short* __restrict__ Bg,
                                                     const float* __restrict__ v_ws,
                                                     float* __restrict__ out)
{
    extern __shared__ __align__(16) unsigned short lds[];   // 2 x 68KB
    const int m0 = blockIdx.x * GBM;    // x = m-tile: x-fast grid keeps resident d-tiles few (B L2-resident)
    const int d0 = blockIdx.y * GDC;
    const int tid = threadIdx.x;
    const int lane = tid & 63, w = tid >> 6;
    const int wr = w >> 1, wn = w & 1;
    const int lg = lane >> 4, lr = lane & 15;

    // --- staging descriptors: slots s = w + i*8 (waves 0-3: 9 slots, 4-7: 8)
    const unsigned short* gsrc[9];
    int loff[9];    // ushort offset within buffer
    int ns = 0;
    {
        const int rsl = lane >> 3;   // row within 8-row slot
        const int c   = lane & 7;    // 16B chunk within 128B row
#pragma unroll
        for (int i = 0; i < 9; ++i) {
            int s = w + i * 8;
            if (s < GTSLOT) {
                if (s < GASLOT) {
                    int row = s * 8 + rsl;                    // 0..255
                    gsrc[ns] = A + (size_t)(m0 + row) * KD + (c ^ (row & 7)) * 8;
                    loff[ns] = s * 512;
                } else {
                    int t = s - GASLOT;
                    int rb = t * 8 + rsl;                     // 0..287
                    int g = rb >> 5, dc = rb & 31;
                    gsrc[ns] = Bg + (size_t)(g * D_DIM + d0 + dc) * KD + (c ^ (rb & 7)) * 8;
                    loff[ns] = GB_OFF_USHORT + t * 512;
                }
                ++ns;
            }
        }
    }

    auto stage = [&](int kt, int buf) {
        const int kof = kt * GBK;
#pragma unroll
        for (int i = 0; i < 9; ++i)
            if (i < ns)
                gload_lds16(gsrc[i] + kof, lds + buf * GBUF_USHORT + loff[i]);
    };

    f32x4 acc[4][NG];
#pragma unroll
    for (int mf = 0; mf < 4; ++mf)
#pragma unroll
        for (int g = 0; g < NG; ++g)
            acc[mf][g] = {0.f, 0.f, 0.f, 0.f};

    stage(0, 0);
    __syncthreads();

    int buf = 0;
    for (int kt = 0; kt < KD / GBK; ++kt) {
        if (kt < KD / GBK - 1) stage(kt + 1, buf ^ 1);   // prefetch next K-tile
        const unsigned short* Lb = lds + buf * GBUF_USHORT;

#pragma unroll
        for (int h = 0; h < 2; ++h) {
            const int cidx = h * 4 + lg;    // 16B chunk 0..7
            short8 af[4], bfr[NG];
#pragma unroll
            for (int mf = 0; mf < 4; ++mf) {
                int ra = wr * 64 + mf * 16 + lr;
                af[mf] = *(const short8*)&Lb[ra * 64 + (cidx ^ (ra & 7)) * 8];
            }
#pragma unroll
            for (int g = 0; g < NG; ++g) {
                int rb = g * 32 + wn * 16 + lr;
                bfr[g] = *(const short8*)&Lb[GB_OFF_USHORT + rb * 64 + (cidx ^ (rb & 7)) * 8];
            }
#pragma unroll
            for (int mf = 0; mf < 4; ++mf)
#pragma unroll
                for (int g = 0; g < NG; ++g)
                    acc[mf][g] = __builtin_amdgcn_mfma_f32_16x16x32_bf16(af[mf], bfr[g], acc[mf][g], 0, 0, 0);
        }
        __syncthreads();   // drains prefetch vmcnt + our lgkm reads
        buf ^= 1;
    }

    // --- epilogue: sigmoid + shifted-v gather + sum over 9 groups
#pragma unroll
    for (int mf = 0; mf < 4; ++mf)
#pragma unroll
        for (int r = 0; r < 4; ++r) {
            const int row = m0 + wr * 64 + mf * 16 + lg * 4 + r;
            const int col = d0 + wn * 16 + lr;
            float o = 0.f;
#pragma unroll
            for (int g = 0; g < NG; ++g) {
                int srow = (row & ~(L_DIM - 1)) | ((row + c_offs[g] + L_DIM) & (L_DIM - 1));
                float gate = 1.f / (1.f + __expf(-acc[mf][g][r]));
                o += gate * v_ws[(size_t)srow * D_DIM + col];
            }
            out[(size_t)row * D_DIM + col] = o;
        }
}

// ---------- in-place LayerNorm over last dim ----------
__global__ __launch_bounds__(256) void ln_kernel(float* __restrict__ out,
                                                 const float* __restrict__ gamma,
                                                 const float* __restrict__ beta)
{
    const int row = blockIdx.x;
    const int tid = threadIdx.x;
    float4 v = *(float4*)&out[(size_t)row * D_DIM + tid * 4];
    float s  = v.x + v.y + v.z + v.w;
    float s2 = v.x * v.x + v.y * v.y + v.z * v.z + v.w * v.w;
#pragma unroll
    for (int off = 32; off > 0; off >>= 1) {
        s  += __shfl_down(s, off, 64);
        s2 += __shfl_down(s2, off, 64);
    }
    __shared__ float sh[8];
    const int wid = tid >> 6, lane = tid & 63;
    if (lane == 0) { sh[wid] = s; sh[4 + wid] = s2; }
    __syncthreads();
    if (tid == 0) {
        float ts = sh[0] + sh[1] + sh[2] + sh[3];
        float t2 = sh[4] + sh[5] + sh[6] + sh[7];
        sh[0] = ts; sh[1] = t2;
    }
    __syncthreads();
    const float mean = sh[0] * (1.f / (float)D_DIM);
    const float var  = sh[1] * (1.f / (float)D_DIM) - mean * mean;
    const float inv  = rsqrtf(var + 1e-5f);
    float4 g = *(const float4*)&gamma[tid * 4];
    float4 b = *(const float4*)&beta[tid * 4];
    v.x = (v.x - mean) * inv * g.x + b.x;
    v.y = (v.y - mean) * inv * g.y + b.y;
    v.z = (v.z - mean) * inv * g.z + b.z;
    v.w = (v.w - mean) * inv * g.w + b.w;
    *(float4*)&out[(size_t)row * D_DIM + tid * 4] = v;
}

extern "C" void kernel_launch(void* const* d_in, const int* in_sizes, int n_in,
                              void* d_out, int out_size, void* d_ws, size_t ws_size,
                              hipStream_t stream) {
    const float* x       = (const float*)d_in[0];   // (4,4096,1024)
    const float* gate_W  = (const float*)d_in[1];   // (9216,1024)
    const float* value_W = (const float*)d_in[2];   // (1024,1024)
    const float* gamma   = (const float*)d_in[3];   // (1024,)
    const float* beta    = (const float*)d_in[4];   // (1024,)
    float* out = (float*)d_out;                     // (4,4096,1024) f32

    char* ws = (char*)d_ws;
    unsigned short* a_bf = (unsigned short*)ws;                      // 32 MB
    unsigned short* bw_v = (unsigned short*)(ws + 33554432);         //  2 MB
    unsigned short* bw_g = (unsigned short*)(ws + 35651584);         // 18 MB
    float*          v_ws = (float*)(ws + 54525952);                  // 64 MB

    // allow 136KB dynamic LDS for gates_gemm (idempotent; not a stream op)
    hipFuncSetAttribute(reinterpret_cast<const void*>(gates_gemm),
                        hipFuncAttributeMaxDynamicSharedMemorySize, 2 * GBUF_USHORT * 2);

    // 1. convert inputs to bf16
    cvt_kernel<<<16384, 256, 0, stream>>>(x,       a_bf, (long)M_TOT * 1024);
    cvt_kernel<<<1024,  256, 0, stream>>>(value_W, bw_v, (long)1024  * 1024);
    cvt_kernel<<<9216,  256, 0, stream>>>(gate_W,  bw_g, (long)9216  * 1024);

    // 2. v = x @ value_W^T   (M=16384, N=1024, K=1024)
    v_gemm<<<dim3(8, 128), 256, 0, stream>>>(a_bf, bw_v, v_ws);

    // 3. gates GEMM (9 groups, one K-pass, BK=64, 8 waves) + sigmoid + shift-gather
    gates_gemm<<<dim3(M_TOT / GBM, D_DIM / GDC), 512, 2 * GBUF_USHORT * 2, stream>>>(a_bf, bw_g, v_ws, out);

    // 4. LayerNorm in place
    ln_kernel<<<16384, 256, 0, stream>>>(out, gamma, beta);
}